// Round 21
// baseline (158.230 us; speedup 1.0000x reference)
//
#include <hip/hip_runtime.h>
#include <math.h>

#define IMGS 16
#define EMB 2400
#define HW 196
#define CAPS 64
#define ATTK 180
#define NPOOL 15
#define NCOLS (IMGS * HW)  // 3136
#define KPAD 224           // 196 padded to multiple of 32

typedef __attribute__((ext_vector_type(8))) short short8;
typedef __attribute__((ext_vector_type(4))) float f32x4;
typedef const __attribute__((address_space(1))) unsigned int* gas1_t;
typedef __attribute__((address_space(3))) unsigned int* las3_t;
typedef unsigned long long ull;

__device__ inline unsigned short f2bf(float f) {
    unsigned int u = __builtin_bit_cast(unsigned int, f);
    u += 0x7fffu + ((u >> 16) & 1u);  // round-to-nearest-even
    return (unsigned short)(u >> 16);
}
__device__ inline float bf2f(unsigned int lo16) {
    return __builtin_bit_cast(float, lo16 << 16);
}
__device__ inline unsigned f2sort(float f) {
    unsigned u = __builtin_bit_cast(unsigned, f);
    int msk = ((int)u) >> 31;
    return u ^ (unsigned)(msk | 0x80000000);
}

// ================= combo bodies (independent roles, one dispatch) =================

// ---- transpool body: transpose+weldon (+optional g passthrough), LDS [32][197] ----
__device__ __forceinline__ void transpool_body(char* smem, int bx, int i,
                                               const float* __restrict__ g,
                                               float* __restrict__ hpool,
                                               unsigned short* __restrict__ gT,
                                               float* __restrict__ gout) {
    float(*t)[197] = (float(*)[197])smem;
    int e0 = bx * 32;
    int tid = threadIdx.x;
    const float* base = g + ((size_t)i * EMB + e0) * HW;
    float* obase = gout ? gout + ((size_t)i * EMB + e0) * HW : nullptr;
    for (int f = tid; f < 32 * HW; f += 256) {
        int e = f / HW, hw = f % HW;
        float v = base[(size_t)e * HW + hw];
        t[e][hw] = v;
        if (obase) obase[(size_t)e * HW + hw] = v;
    }
    __syncthreads();
    for (int f = tid; f < HW * 32; f += 256) {
        int hw = f / 32, e = f % 32;
        gT[((size_t)i * HW + hw) * EMB + e0 + e] = f2bf(t[e][hw]);
    }
    int w = tid >> 6, tl = tid & 63, hl = tl & 31;
    bool negh = tl >= 32;
#pragma unroll 1
    for (int rq = 0; rq < 2; ++rq) {  // row QUADS: 4 independent DPP chains
        int eb = w * 8 + rq * 4;
        float s[4][7];
#pragma unroll
        for (int r = 0; r < 4; r++) {
#pragma unroll
            for (int q = 0; q < 7; q++) {
                int hw = hl + 32 * q;
                if (hw < HW) {
                    unsigned u = __builtin_bit_cast(unsigned, t[eb + r][hw]);
                    if (negh) u ^= 0x80000000u;  // negate for bottom-15
                    s[r][q] = __builtin_bit_cast(
                        float, (u & 0xFFFFFF00u) | (unsigned)(q * 32 + hl));
                } else {
                    s[r][q] = -INFINITY;
                }
            }
        }
#define CS1(r, a, b)                                       \
    {                                                      \
        float hi = fmaxf(s[r][a], s[r][b]);                \
        float lo = fminf(s[r][a], s[r][b]);                \
        s[r][a] = hi; s[r][b] = lo;                        \
    }
#define CSQ(a, b) CS1(0, a, b) CS1(1, a, b) CS1(2, a, b) CS1(3, a, b)
        CSQ(1, 2) CSQ(3, 4) CSQ(5, 6)
        CSQ(0, 2) CSQ(3, 5) CSQ(4, 6)
        CSQ(0, 1) CSQ(4, 5) CSQ(2, 6)
        CSQ(0, 4) CSQ(1, 5)
        CSQ(0, 3) CSQ(2, 5)
        CSQ(1, 3) CSQ(2, 4)
        CSQ(2, 3)
#undef CSQ
#undef CS1
        float acc[4] = {0.f, 0.f, 0.f, 0.f};
#pragma unroll
        for (int it = 0; it < NPOOL; ++it) {
            int xx[4];
#pragma unroll
            for (int r = 0; r < 4; r++) xx[r] = __builtin_bit_cast(int, s[r][0]);
#define ST4(c)                                                                     \
    {                                                                              \
        _Pragma("unroll") for (int r = 0; r < 4; r++) {                            \
            int y = __builtin_amdgcn_update_dpp(xx[r], xx[r], c, 0xf, 0xf, false); \
            float a = fmaxf(__builtin_bit_cast(float, xx[r]),                      \
                            __builtin_bit_cast(float, y));                         \
            xx[r] = __builtin_bit_cast(int, a);                                    \
        }                                                                          \
    }
            ST4(0x111) ST4(0x112) ST4(0x114) ST4(0x118) ST4(0x142)
#undef ST4
#pragma unroll
            for (int r = 0; r < 4; r++) {
                int m31 = __builtin_amdgcn_readlane(xx[r], 31);
                int m63 = __builtin_amdgcn_readlane(xx[r], 63);
                float msel = __builtin_bit_cast(float, negh ? m63 : m31);
                acc[r] += msel;
                bool won = (__builtin_bit_cast(unsigned, s[r][0]) ==
                            __builtin_bit_cast(unsigned, msel));
                s[r][0] = won ? s[r][1] : s[r][0];
                s[r][1] = won ? s[r][2] : s[r][1];
                s[r][2] = won ? s[r][3] : s[r][2];
                s[r][3] = won ? s[r][4] : s[r][3];
                s[r][4] = won ? s[r][5] : s[r][4];
                s[r][5] = won ? s[r][6] : s[r][5];
                s[r][6] = won ? -INFINITY : s[r][6];
            }
        }
#pragma unroll
        for (int r = 0; r < 4; r++) {
            int ai = __builtin_bit_cast(int, acc[r]);
            float a0 = __builtin_bit_cast(float, __builtin_amdgcn_readlane(ai, 0));
            float a32 = __builtin_bit_cast(float, __builtin_amdgcn_readlane(ai, 32));
            if (tl == 0) hpool[(size_t)i * EMB + e0 + eb + r] = (a0 - a32) / 15.0f;
        }
    }
}

// ---- topk body: radix select, wave-level scans ----
__device__ __forceinline__ void topk_body(char* smem, int c,
                                          const float* __restrict__ caps,
                                          int* __restrict__ idxs,
                                          float* __restrict__ vals) {
    float* rowf = (float*)smem;                                // 9600 B
    unsigned(*hist)[256] = (unsigned(*)[256])(smem + 9600);    // 4096 B
    unsigned* scanbuf = (unsigned*)(smem + 13696);             // 1024 B
    unsigned* wtot = (unsigned*)(smem + 14720);                // 16 B
    ull* sprefix = (ull*)(smem + 14744);                       // 8 B
    int* srank = (int*)(smem + 14752);                         // 4 B
    int tid = threadIdx.x;
    int w = tid >> 6, lane = tid & 63;
    const float4* src = (const float4*)(caps + (size_t)c * EMB);
    for (int j = tid; j < EMB / 4; j += 256) {
        float4 v = src[j];
        *(float4*)&rowf[j * 4] = v;
    }
    if (tid == 0) { *sprefix = 0ull; *srank = ATTK; }
#pragma unroll 1
    for (int pass = 0; pass < 6; ++pass) {
        __syncthreads();
        ull pref = *sprefix;
        int rk = *srank;
        int shift = 40 - pass * 8;
        ull pmaskhi = (pass == 0) ? 0ull : ~((1ull << (shift + 8)) - 1ull);
        hist[0][tid] = 0; hist[1][tid] = 0; hist[2][tid] = 0; hist[3][tid] = 0;
        __syncthreads();
        unsigned* myhist = hist[w];
#pragma unroll 1
        for (int s = 0; s < 10; s++) {
            int e = tid + s * 256;
            if (e < EMB) {
                ull key = ((ull)f2sort(rowf[e]) << 16) | ((unsigned)(2399 - e) << 4);
                if ((key & pmaskhi) == pref)
                    atomicAdd(&myhist[(unsigned)(key >> shift) & 255u], 1u);
            }
        }
        __syncthreads();
        unsigned h = hist[0][tid] + hist[1][tid] + hist[2][tid] + hist[3][tid];
        scanbuf[255 - tid] = h;
        __syncthreads();
        unsigned x = scanbuf[tid];
#pragma unroll
        for (int d = 1; d < 64; d <<= 1) {
            unsigned u = __shfl_up(x, d, 64);
            if (lane >= d) x += u;
        }
        if (lane == 63) wtot[w] = x;
        __syncthreads();
        unsigned off = 0;
        for (int ww = 0; ww < w; ww++) off += wtot[ww];
        scanbuf[tid] = x + off;
        __syncthreads();
        unsigned incl = scanbuf[255 - tid];
        unsigned excl = incl - h;
        if (h > 0u && excl < (unsigned)rk && incl >= (unsigned)rk) {
            *srank = rk - (int)excl;
            *sprefix = pref | ((ull)tid << shift);
        }
    }
    __syncthreads();
    ull T = *sprefix;
    unsigned selmask = 0, cnt = 0;
#pragma unroll 1
    for (int s = 0; s < 10; s++) {
        int e = tid + s * 256;
        if (e < EMB) {
            ull key = ((ull)f2sort(rowf[e]) << 16) | ((unsigned)(2399 - e) << 4);
            if (key >= T) { selmask |= 1u << s; cnt++; }
        }
    }
    unsigned x = cnt;
#pragma unroll
    for (int d = 1; d < 64; d <<= 1) {
        unsigned u = __shfl_up(x, d, 64);
        if (lane >= d) x += u;
    }
    if (lane == 63) wtot[w] = x;
    __syncthreads();
    unsigned off = 0;
    for (int ww = 0; ww < w; ww++) off += wtot[ww];
    unsigned slot = x + off - cnt;
#pragma unroll 1
    for (int s = 0; s < 10; s++) {
        if (selmask & (1u << s)) {
            int e = tid + s * 256;
            idxs[c * ATTK + slot] = e;
            vals[c * ATTK + slot] = fabsf(rowf[e]);
            slot++;
        }
    }
}

// ---- convw body: wbf = bf16(fc_w), 4 rows/block ----
__device__ __forceinline__ void convw_body(int b, const float* __restrict__ fc_w,
                                           unsigned short* __restrict__ wbf) {
    int o = b * 4 + (threadIdx.x >> 6);
    int lane = threadIdx.x & 63;
    const float* wrow = fc_w + (size_t)o * EMB;
    unsigned short* wdst = wbf + (size_t)o * EMB;
    for (int e = lane * 4; e < EMB; e += 256) {
        float4 wv = *(const float4*)&wrow[e];
        ushort4 r;
        r.x = f2bf(wv.x); r.y = f2bf(wv.y); r.z = f2bf(wv.z); r.w = f2bf(wv.w);
        *(ushort4*)&wdst[e] = r;
    }
}

// ---- combo dispatcher: [transpool 1200][convw 600][topk 64] ----
__global__ __launch_bounds__(256) void combo_kernel(const float* __restrict__ g,
                                                    float* __restrict__ hpool,
                                                    unsigned short* __restrict__ gT,
                                                    float* __restrict__ gout,
                                                    const float* __restrict__ caps,
                                                    int* __restrict__ idxs,
                                                    float* __restrict__ vals,
                                                    const float* __restrict__ fc_w,
                                                    unsigned short* __restrict__ wbf,
                                                    int nconv) {
    __shared__ __align__(16) char smem[25664];
    int b = blockIdx.x;
    constexpr int NTP = (EMB / 32) * IMGS;  // 1200
    if (b < NTP) {
        transpool_body(smem, b % (EMB / 32), b / (EMB / 32), g, hpool, gT, gout);
    } else if (b < NTP + nconv) {
        convw_body(b - NTP, fc_w, wbf);
    } else {
        topk_body(smem, b - NTP - nconv, caps, idxs, vals);
    }
}

// ---------------- x (fallback, fp32 weights) ----------------
__global__ void x_kernel(const float* __restrict__ hpool, const float* __restrict__ fc_w,
                         const float* __restrict__ fc_b, float* __restrict__ x_out) {
    int o = blockIdx.x;
    int lane = threadIdx.x;
    float acc[IMGS];
#pragma unroll
    for (int i = 0; i < IMGS; i++) acc[i] = 0.f;
    const float* wrow = fc_w + (size_t)o * EMB;
    for (int e = lane; e < EMB; e += 64) {
        float wv = wrow[e];
#pragma unroll
        for (int i = 0; i < IMGS; i++) acc[i] += hpool[i * EMB + e] * wv;
    }
#pragma unroll
    for (int i = 0; i < IMGS; i++) {
#pragma unroll
        for (int sdx = 32; sdx > 0; sdx >>= 1) acc[i] += __shfl_xor(acc[i], sdx, 64);
    }
    if (lane == 0) {
        float bo = fc_b[o];
#pragma unroll
        for (int i = 0; i < IMGS; i++) x_out[i * EMB + o] = acc[i] + bo;
    }
}

// ======== NT bf16 MFMA GEMM, gll staging, 3-buffer counted-vmcnt pipeline ========
// T1 bijective XCD swizzle + y-major; T2 source/read swizzle; T4 counted vmcnt;
// T5 setprio. OUT_MODE 6: signed bf16; 7: signed bf16 at z*M*N (split-K partial);
// 4: f32 v*invS[z*64+row]+bias[col] (batched).
// r21: split-K support -- nt clamps to K-kb so kper can be non-divisor (1216/1184).
template <int MF, int NF, int OUT_MODE>
__global__ __launch_bounds__(256) void gemm_gll(const unsigned short* __restrict__ A,
                                                const unsigned short* __restrict__ B,
                                                void* __restrict__ outp,
                                                const float* __restrict__ bias,
                                                const float* __restrict__ invS,
                                                int M, int N, int K, int ldb, int kper,
                                                long az, long bz) {
    constexpr int BM = MF * 32, BN = NF * 32;
    constexpr int ROWS = BM + BN;
    constexpr int RPAD = (ROWS + 63) & ~63;
    constexpr int NCALL = RPAD / 16;
    constexpr int LPW = NCALL / 4;
    __shared__ unsigned short lds[3][RPAD][32];
    int gx = gridDim.x, gy = gridDim.y;
    int nwg = gx * gy;
    int flat = blockIdx.y * gx + blockIdx.x;
    int qq = nwg >> 3, rr8 = nwg & 7;
    int xcd = flat & 7, idx = flat >> 3;
    int base = (xcd < rr8) ? xcd * (qq + 1) : rr8 * (qq + 1) + (xcd - rr8) * qq;
    int nf = base + idx;
    int m0 = (nf % gy) * BM;
    int n0 = (nf / gy) * BN;
    int z = blockIdx.z;
    const unsigned short* Ab = A + (size_t)z * az;
    const unsigned short* Bb = B + (size_t)z * bz;
    int kb, nt;
    if (az == 0 && bz == 0) {
        kb = z * kper;
        int kc = K - kb;
        if (kc > kper) kc = kper;
        nt = kc / 32;
    } else {
        kb = 0;
        nt = kper / 32;
    }
    int tid = threadIdx.x, w = tid >> 6, lane = tid & 63;
    int wm = (w >> 1) * (MF * 16), wn = (w & 1) * (NF * 16);
    int ln = lane & 15;
    int ks = (((lane >> 4) ^ ((lane >> 1) & 3))) * 8;
    int srow = lane >> 2;
    int skc = (((lane & 3) ^ ((lane >> 3) & 3))) * 8;

    auto STAGE = [&](int buf, int t) {
        int k0 = kb + t * 32;
#pragma unroll
        for (int j = 0; j < LPW; j++) {
            int jj = w + j * 4;
            int r = jj * 16 + srow;
            const unsigned short* src;
            if (r < BM) src = Ab + (size_t)(m0 + r) * K + k0 + skc;
            else if (r < ROWS) src = Bb + (size_t)(n0 + r - BM) * ldb + k0 + skc;
            else src = Ab + (size_t)m0 * K + k0 + skc;  // dummy (uniform vmcnt)
            __builtin_amdgcn_global_load_lds((gas1_t)(const void*)src,
                                             (las3_t)(void*)&lds[buf][jj * 16][0], 16, 0, 0);
        }
    };

    STAGE(0, 0);
    if (nt > 1) STAGE(1, 1);
    f32x4 acc[MF][NF] = {};
    for (int t = 0; t < nt; ++t) {
        if (t + 1 < nt) {
            if constexpr (LPW == 4) asm volatile("s_waitcnt vmcnt(4) lgkmcnt(0)" ::: "memory");
            else if constexpr (LPW == 5) asm volatile("s_waitcnt vmcnt(5) lgkmcnt(0)" ::: "memory");
            else if constexpr (LPW == 6) asm volatile("s_waitcnt vmcnt(6) lgkmcnt(0)" ::: "memory");
            else asm volatile("s_waitcnt vmcnt(0) lgkmcnt(0)" ::: "memory");
        } else {
            asm volatile("s_waitcnt vmcnt(0) lgkmcnt(0)" ::: "memory");
        }
        __builtin_amdgcn_s_barrier();
        __builtin_amdgcn_sched_barrier(0);  // rule #18
        if (t + 2 < nt) STAGE((t + 2) % 3, t + 2);
        const unsigned short(*buf)[32] = lds[t % 3];
        short8 af[MF], bfv[NF];
#pragma unroll
        for (int mf = 0; mf < MF; mf++)
            af[mf] = *(const short8*)&buf[wm + mf * 16 + ln][ks];
#pragma unroll
        for (int nfi = 0; nfi < NF; nfi++)
            bfv[nfi] = *(const short8*)&buf[BM + wn + nfi * 16 + ln][ks];
        __builtin_amdgcn_s_setprio(1);  // T5
#pragma unroll
        for (int mf = 0; mf < MF; mf++)
#pragma unroll
            for (int nfi = 0; nfi < NF; nfi++)
                acc[mf][nfi] = __builtin_amdgcn_mfma_f32_16x16x32_bf16(af[mf], bfv[nfi],
                                                                       acc[mf][nfi], 0, 0, 0);
        __builtin_amdgcn_s_setprio(0);
    }
#pragma unroll
    for (int mf = 0; mf < MF; mf++) {
#pragma unroll
        for (int nfi = 0; nfi < NF; nfi++) {
#pragma unroll
            for (int rr = 0; rr < 4; rr++) {
                int row = m0 + wm + mf * 16 + (lane >> 4) * 4 + rr;
                int col = n0 + wn + nfi * 16 + ln;
                float v = acc[mf][nfi][rr];
                if (OUT_MODE == 6) {
                    ((unsigned short*)outp)[(size_t)row * N + col] = f2bf(v);
                } else if (OUT_MODE == 7) {
                    ((unsigned short*)outp)[(size_t)z * M * N + (size_t)row * N + col] =
                        f2bf(v);
                } else if (OUT_MODE == 4) {
                    ((float*)outp)[((size_t)z * CAPS + row) * N + col] =
                        v * invS[z * CAPS + row] + bias[col];
                }
            }
        }
    }
}

// ---- reduceA: Asig = bf16(P0 + P1), in place at P0 (huge tier only) ----
__global__ __launch_bounds__(256) void reduceA_kernel(unsigned short* pp) {
    const size_t S = (size_t)EMB * NCOLS;
    size_t i = ((size_t)blockIdx.x * 256 + threadIdx.x) * 8;
    if (i >= S) return;
    ushort4 a0 = *(const ushort4*)&pp[i];
    ushort4 a1 = *(const ushort4*)&pp[i + 4];
    ushort4 b0 = *(const ushort4*)&pp[S + i];
    ushort4 b1 = *(const ushort4*)&pp[S + i + 4];
    ushort4 r0, r1;
    r0.x = f2bf(bf2f(a0.x) + bf2f(b0.x));
    r0.y = f2bf(bf2f(a0.y) + bf2f(b0.y));
    r0.z = f2bf(bf2f(a0.z) + bf2f(b0.z));
    r0.w = f2bf(bf2f(a0.w) + bf2f(b0.w));
    r1.x = f2bf(bf2f(a1.x) + bf2f(b1.x));
    r1.y = f2bf(bf2f(a1.y) + bf2f(b1.y));
    r1.z = f2bf(bf2f(a1.z) + bf2f(b1.z));
    r1.w = f2bf(bf2f(a1.w) + bf2f(b1.w));
    *(ushort4*)&pp[i] = r0;
    *(ushort4*)&pp[i + 4] = r1;
}

// ======== fallback reg-staged NT GEMM (gemm1 only; used if ws too small for wbf) ========
__device__ inline uint4 load8(const unsigned short* p) { return *(const uint4*)p; }
__device__ inline uint4 load8(const float* p) {
    float4 a = *(const float4*)p;
    float4 b = *(const float4*)(p + 4);
    uint4 r;
    r.x = (unsigned)f2bf(a.x) | ((unsigned)f2bf(a.y) << 16);
    r.y = (unsigned)f2bf(a.z) | ((unsigned)f2bf(a.w) << 16);
    r.z = (unsigned)f2bf(b.x) | ((unsigned)f2bf(b.y) << 16);
    r.w = (unsigned)f2bf(b.z) | ((unsigned)f2bf(b.w) << 16);
    return r;
}

template <int MF, int NF, typename TA, typename TB>
__global__ __launch_bounds__(256) void mfma_gemm_nt(const TA* __restrict__ A,
                                                    const TB* __restrict__ B,
                                                    void* __restrict__ outp,
                                                    int M, int N, int K) {
    constexpr int BM = MF * 32, BN = NF * 32;
    constexpr int nA = BM * 4, nTot = (BM + BN) * 4;
    constexpr int NCH = (nTot + 255) / 256;
    __shared__ unsigned short As[BM][40];
    __shared__ unsigned short Bs[BN][40];
    int m0 = blockIdx.y * BM, n0 = blockIdx.x * BN;
    int tid = threadIdx.x;
    int w = tid >> 6, lane = tid & 63;
    int wm = (w >> 1) * (MF * 16), wn = (w & 1) * (NF * 16);
    int ln = lane & 15, ks = (lane >> 4) * 8;
    uint4 r[NCH];
#pragma unroll
    for (int j = 0; j < NCH; j++) {
        int c = tid + 256 * j;
        if (c < nTot) {
            if (c < nA) {
                int row = c >> 2, kc = c & 3;
                r[j] = load8(A + (size_t)(m0 + row) * K + kc * 8);
            } else {
                int cc = c - nA, row = cc >> 2, kc = cc & 3;
                r[j] = load8(B + (size_t)(n0 + row) * K + kc * 8);
            }
        }
    }
    f32x4 acc[MF][NF] = {};
    for (int k0 = 0; k0 < K; k0 += 32) {
#pragma unroll
        for (int j = 0; j < NCH; j++) {
            int c = tid + 256 * j;
            if (c < nTot) {
                if (c < nA) {
                    int row = c >> 2, kc = c & 3;
                    *(uint4*)&As[row][kc * 8] = r[j];
                } else {
                    int cc = c - nA, row = cc >> 2, kc = cc & 3;
                    *(uint4*)&Bs[row][kc * 8] = r[j];
                }
            }
        }
        __syncthreads();
        if (k0 + 32 < K) {
#pragma unroll
            for (int j = 0; j < NCH; j++) {
                int c = tid + 256 * j;
                if (c < nTot) {
                    if (c < nA) {
                        int row = c >> 2, kc = c & 3;
                        r[j] = load8(A + (size_t)(m0 + row) * K + (k0 + 32) + kc * 8);
                    } else {
                        int cc = c - nA, row = cc >> 2, kc = cc & 3;
                        r[j] = load8(B + (size_t)(n0 + row) * K + (k0 + 32) + kc * 8);
                    }
                }
            }
        }
        short8 af[MF], bfv[NF];
#pragma unroll
        for (int mf = 0; mf < MF; mf++)
            af[mf] = *(const short8*)&As[wm + mf * 16 + ln][ks];
#pragma unroll
        for (int nfi = 0; nfi < NF; nfi++)
            bfv[nfi] = *(const short8*)&Bs[wn + nfi * 16 + ln][ks];
#pragma unroll
        for (int mf = 0; mf < MF; mf++)
#pragma unroll
            for (int nfi = 0; nfi < NF; nfi++)
                acc[mf][nfi] = __builtin_amdgcn_mfma_f32_16x16x32_bf16(af[mf], bfv[nfi],
                                                                       acc[mf][nfi], 0, 0, 0);
        __syncthreads();
    }
#pragma unroll
    for (int mf = 0; mf < MF; mf++) {
#pragma unroll
        for (int nfi = 0; nfi < NF; nfi++) {
#pragma unroll
            for (int rr = 0; rr < 4; rr++) {
                int row = m0 + wm + mf * 16 + (lane >> 4) * 4 + rr;
                int col = n0 + wn + nfi * 16 + ln;
                ((unsigned short*)outp)[(size_t)row * N + col] = f2bf(acc[mf][nfi][rr]);
            }
        }
    }
}

// ======== heatx: heat (i,c)-blocks + x_bf blocks in one dispatch ========
__global__ __launch_bounds__(256) void heatx_kernel(const int* __restrict__ idxs,
                                                    const float* __restrict__ vals,
                                                    const unsigned short* __restrict__ A,
                                                    unsigned short* __restrict__ Hnbf,
                                                    float* __restrict__ invS,
                                                    const float* __restrict__ hpool,
                                                    const unsigned short* __restrict__ wbf,
                                                    const float* __restrict__ fc_b,
                                                    float* __restrict__ x_out,
                                                    int nheat) {
    __shared__ int sidx[ATTK];
    __shared__ float sval[ATTK];
    __shared__ float wsum[4];
    int b = blockIdx.x;
    int tid = threadIdx.x;
    int w = tid >> 6, lane = tid & 63;
    if (b < nheat) {
        int i = b % IMGS, c = b / IMGS;
        if (tid < ATTK) {
            sidx[tid] = idxs[c * ATTK + tid];
            sval[tid] = vals[c * ATTK + tid];
        }
        __syncthreads();
        int hw = tid;
        float v = 0.f;
        if (hw < HW) {
            int n = i * HW + hw;
            float a0 = 0.f, a1 = 0.f, a2 = 0.f, a3 = 0.f;
#pragma unroll 1
            for (int j = 0; j < ATTK; j += 4) {
                a0 += sval[j + 0] * bf2f(A[(size_t)sidx[j + 0] * NCOLS + n] & 0x7FFFu);
                a1 += sval[j + 1] * bf2f(A[(size_t)sidx[j + 1] * NCOLS + n] & 0x7FFFu);
                a2 += sval[j + 2] * bf2f(A[(size_t)sidx[j + 2] * NCOLS + n] & 0x7FFFu);
                a3 += sval[j + 3] * bf2f(A[(size_t)sidx[j + 3] * NCOLS + n] & 0x7FFFu);
            }
            v = (a0 + a1) + (a2 + a3);
        }
        if (hw < KPAD)
            Hnbf[((size_t)i * CAPS + c) * KPAD + hw] =
                (hw < HW) ? f2bf(v) : (unsigned short)0;
        float s = v;
#pragma unroll
        for (int d = 32; d > 0; d >>= 1) s += __shfl_xor(s, d, 64);
        if (lane == 0) wsum[w] = s;
        __syncthreads();
        if (tid == 0)
            invS[i * CAPS + c] = 1.0f / (wsum[0] + wsum[1] + wsum[2] + wsum[3]);
    } else {
        int o = (b - nheat) * 4 + w;
        float acc[IMGS];
#pragma unroll
        for (int i = 0; i < IMGS; i++) acc[i] = 0.f;
        const unsigned short* wrow = wbf + (size_t)o * EMB;
        for (int e = lane * 4; e < EMB; e += 256) {
            ushort4 wq = *(const ushort4*)&wrow[e];
            float w0 = bf2f(wq.x), w1 = bf2f(wq.y), w2 = bf2f(wq.z), w3 = bf2f(wq.w);
#pragma unroll
            for (int i = 0; i < IMGS; i++) {
                const float* hp = hpool + i * EMB + e;
                acc[i] += hp[0] * w0 + hp[1] * w1 + hp[2] * w2 + hp[3] * w3;
            }
        }
#pragma unroll
        for (int i = 0; i < IMGS; i++) {
#pragma unroll
            for (int sdx = 32; sdx > 0; sdx >>= 1) acc[i] += __shfl_xor(acc[i], sdx, 64);
        }
        if (lane == 0) {
            float bo = fc_b[o];
#pragma unroll
            for (int i = 0; i < IMGS; i++) x_out[i * EMB + o] = acc[i] + bo;
        }
    }
}

extern "C" void kernel_launch(void* const* d_in, const int* in_sizes, int n_in,
                              void* d_out, int out_size, void* d_ws, size_t ws_size,
                              hipStream_t stream) {
    const float* g = (const float*)d_in[0];
    const float* caps = (const float*)d_in[1];
    const float* fc_w = (const float*)d_in[2];
    const float* fc_b = (const float*)d_in[3];

    float* out = (float*)d_out;
    float* x_out = out;                    // 38400
    float* xa_out = out + 38400;           // 2457600
    float* g_out = out + 38400 + 2457600;  // 7526400 floats = 30.1 MB

    const size_t S = (size_t)EMB * NCOLS;  // 7,526,400 elements (15.05 MB bf16)
    float* ws = (float*)d_ws;
    float* hpool = ws;                                       // 38400 f
    int* idxs = (int*)(ws + 38400);                          // 11520
    float* vals = ws + 49920;                                // 11520
    float* invS = ws + 61440;                                // 1024 f
    unsigned short* Hnbf = (unsigned short*)(ws + 62464);    // 16*64*224 us
    unsigned short* wbf = (unsigned short*)(ws + 1490944);   // ends byte 17483776
    bool use_wbf = ws_size >= (size_t)17483776;
    bool ws_big = use_wbf && ws_size >= (size_t)(17483776 + 2 * 15052800);   // 47.6 MB
    bool ws_huge = use_wbf && ws_size >= (size_t)(17483776 + 3 * 15052800);  // 62.6 MB

    // tier layouts (Asig always followed by initialized data for the xa K-tail):
    //   huge: [wbf][P0=Asig][P1][gT]  (split-K gemm1, reduceA sums into Asig)
    //   big : [wbf][gT][Asig]         (single-pass gemm1)
    //   else: Asig/gT in g_out, memcpy at end
    unsigned short* Asig;
    unsigned short* gT;
    if (ws_huge) {
        Asig = (unsigned short*)((char*)d_ws + 17483776);
        gT = Asig + 2 * S;
    } else if (ws_big) {
        gT = (unsigned short*)((char*)d_ws + 17483776);
        Asig = gT + S;
    } else {
        Asig = (unsigned short*)g_out;
        gT = Asig + S;
    }

    if (use_wbf) {
        // combo: [transpool 1200][convw 600][topk 64]
        combo_kernel<<<(EMB / 32) * IMGS + EMB / 4 + CAPS, 256, 0, stream>>>(
            g, hpool, gT, ws_big ? g_out : nullptr, caps, idxs, vals, fc_w, wbf, EMB / 4);
        if (ws_huge) {
            // gemm1 split-K x2: 420 blocks = 2 blocks/CU co-resident (r4 mechanism);
            // kper=1216 -> z=0 nt=38, z=1 nt=37 (runtime clamp). Partials P0||P1.
            gemm_gll<5, 7, 7><<<dim3(NCOLS / 224, EMB / 160, 2), 256, 0, stream>>>(
                wbf, gT, Asig, nullptr, nullptr, EMB, NCOLS, EMB, EMB, 1216, 0, 0);
            reduceA_kernel<<<(int)(S / 8 / 256), 256, 0, stream>>>(Asig);
        } else {
            gemm_gll<5, 7, 6><<<dim3(NCOLS / 224, EMB / 160, 1), 256, 0, stream>>>(
                wbf, gT, Asig, nullptr, nullptr, EMB, NCOLS, EMB, EMB, EMB, 0, 0);
        }
        // heat (1024 blocks) + x_bf (600 blocks) co-dispatched
        heatx_kernel<<<IMGS * CAPS + EMB / 4, 256, 0, stream>>>(
            idxs, vals, Asig, Hnbf, invS, hpool, wbf, fc_b, x_out, IMGS * CAPS);
    } else {
        combo_kernel<<<(EMB / 32) * IMGS + CAPS, 256, 0, stream>>>(
            g, hpool, gT, nullptr, caps, idxs, vals, fc_w, nullptr, 0);
        x_kernel<<<EMB, 64, 0, stream>>>(hpool, fc_w, fc_b, x_out);
        mfma_gemm_nt<5, 2, float, unsigned short>
            <<<dim3(NCOLS / 64, EMB / 160), 256, 0, stream>>>(fc_w, gT, Asig,
                                                              EMB, NCOLS, EMB);
        heatx_kernel<<<IMGS * CAPS, 256, 0, stream>>>(
            idxs, vals, Asig, Hnbf, invS, hpool, nullptr, fc_b, x_out, IMGS * CAPS);
    }
    // xa = (Hraw_i @ Asig_i^T) * invS + bias : per-image batched GEMM
    gemm_gll<2, 5, 4><<<dim3(EMB / 160, 1, IMGS), 256, 0, stream>>>(
        Hnbf, Asig, xa_out, fc_b, invS, CAPS, EMB, KPAD, NCOLS, KPAD,
        (long)CAPS * KPAD, HW);
    if (!ws_big) {
        hipMemcpyAsync(g_out, g, sizeof(float) * (size_t)IMGS * EMB * HW,
                       hipMemcpyDeviceToDevice, stream);
    }
}

// Round 22
// 146.934 us; speedup vs baseline: 1.0769x; 1.0769x over previous
//
#include <hip/hip_runtime.h>
#include <math.h>

#define IMGS 16
#define EMB 2400
#define HW 196
#define CAPS 64
#define ATTK 180
#define NPOOL 15
#define NCOLS (IMGS * HW)  // 3136
#define KPAD 224           // 196 padded to multiple of 32

typedef __attribute__((ext_vector_type(8))) short short8;
typedef __attribute__((ext_vector_type(4))) float f32x4;
typedef const __attribute__((address_space(1))) unsigned int* gas1_t;
typedef __attribute__((address_space(3))) unsigned int* las3_t;
typedef unsigned long long ull;

__device__ inline unsigned short f2bf(float f) {
    unsigned int u = __builtin_bit_cast(unsigned int, f);
    u += 0x7fffu + ((u >> 16) & 1u);  // round-to-nearest-even
    return (unsigned short)(u >> 16);
}
__device__ inline float bf2f(unsigned int lo16) {
    return __builtin_bit_cast(float, lo16 << 16);
}
__device__ inline unsigned f2sort(float f) {
    unsigned u = __builtin_bit_cast(unsigned, f);
    int msk = ((int)u) >> 31;
    return u ^ (unsigned)(msk | 0x80000000);
}

// ================= combo bodies (independent roles, one dispatch) =================
// r22 = r20 revert (r21 split-K gemm1 regressed: reduceA +9us traffic, no overlap
// gain at 2 blocks/CU). Weldon: 4 independent DPP chains (r20).

// ---- transpool body: transpose+weldon (+optional g passthrough), LDS [32][197] ----
__device__ __forceinline__ void transpool_body(char* smem, int bx, int i,
                                               const float* __restrict__ g,
                                               float* __restrict__ hpool,
                                               unsigned short* __restrict__ gT,
                                               float* __restrict__ gout) {
    float(*t)[197] = (float(*)[197])smem;
    int e0 = bx * 32;
    int tid = threadIdx.x;
    const float* base = g + ((size_t)i * EMB + e0) * HW;
    float* obase = gout ? gout + ((size_t)i * EMB + e0) * HW : nullptr;
    for (int f = tid; f < 32 * HW; f += 256) {
        int e = f / HW, hw = f % HW;
        float v = base[(size_t)e * HW + hw];
        t[e][hw] = v;
        if (obase) obase[(size_t)e * HW + hw] = v;
    }
    __syncthreads();
    for (int f = tid; f < HW * 32; f += 256) {
        int hw = f / 32, e = f % 32;
        gT[((size_t)i * HW + hw) * EMB + e0 + e] = f2bf(t[e][hw]);
    }
    int w = tid >> 6, tl = tid & 63, hl = tl & 31;
    bool negh = tl >= 32;
#pragma unroll 1
    for (int rq = 0; rq < 2; ++rq) {  // row QUADS: 4 independent DPP chains
        int eb = w * 8 + rq * 4;
        float s[4][7];
#pragma unroll
        for (int r = 0; r < 4; r++) {
#pragma unroll
            for (int q = 0; q < 7; q++) {
                int hw = hl + 32 * q;
                if (hw < HW) {
                    unsigned u = __builtin_bit_cast(unsigned, t[eb + r][hw]);
                    if (negh) u ^= 0x80000000u;  // negate for bottom-15
                    s[r][q] = __builtin_bit_cast(
                        float, (u & 0xFFFFFF00u) | (unsigned)(q * 32 + hl));
                } else {
                    s[r][q] = -INFINITY;
                }
            }
        }
        // Bose-Nelson sort-7 (desc) x4, interleaved
#define CS1(r, a, b)                                       \
    {                                                      \
        float hi = fmaxf(s[r][a], s[r][b]);                \
        float lo = fminf(s[r][a], s[r][b]);                \
        s[r][a] = hi; s[r][b] = lo;                        \
    }
#define CSQ(a, b) CS1(0, a, b) CS1(1, a, b) CS1(2, a, b) CS1(3, a, b)
        CSQ(1, 2) CSQ(3, 4) CSQ(5, 6)
        CSQ(0, 2) CSQ(3, 5) CSQ(4, 6)
        CSQ(0, 1) CSQ(4, 5) CSQ(2, 6)
        CSQ(0, 4) CSQ(1, 5)
        CSQ(0, 3) CSQ(2, 5)
        CSQ(1, 3) CSQ(2, 4)
        CSQ(2, 3)
#undef CSQ
#undef CS1
        float acc[4] = {0.f, 0.f, 0.f, 0.f};
#pragma unroll
        for (int it = 0; it < NPOOL; ++it) {
            int xx[4];
#pragma unroll
            for (int r = 0; r < 4; r++) xx[r] = __builtin_bit_cast(int, s[r][0]);
#define ST4(c)                                                                     \
    {                                                                              \
        _Pragma("unroll") for (int r = 0; r < 4; r++) {                            \
            int y = __builtin_amdgcn_update_dpp(xx[r], xx[r], c, 0xf, 0xf, false); \
            float a = fmaxf(__builtin_bit_cast(float, xx[r]),                      \
                            __builtin_bit_cast(float, y));                         \
            xx[r] = __builtin_bit_cast(int, a);                                    \
        }                                                                          \
    }
            ST4(0x111) ST4(0x112) ST4(0x114) ST4(0x118) ST4(0x142)
#undef ST4
#pragma unroll
            for (int r = 0; r < 4; r++) {
                int m31 = __builtin_amdgcn_readlane(xx[r], 31);
                int m63 = __builtin_amdgcn_readlane(xx[r], 63);
                float msel = __builtin_bit_cast(float, negh ? m63 : m31);
                acc[r] += msel;
                bool won = (__builtin_bit_cast(unsigned, s[r][0]) ==
                            __builtin_bit_cast(unsigned, msel));
                s[r][0] = won ? s[r][1] : s[r][0];
                s[r][1] = won ? s[r][2] : s[r][1];
                s[r][2] = won ? s[r][3] : s[r][2];
                s[r][3] = won ? s[r][4] : s[r][3];
                s[r][4] = won ? s[r][5] : s[r][4];
                s[r][5] = won ? s[r][6] : s[r][5];
                s[r][6] = won ? -INFINITY : s[r][6];
            }
        }
#pragma unroll
        for (int r = 0; r < 4; r++) {
            int ai = __builtin_bit_cast(int, acc[r]);
            float a0 = __builtin_bit_cast(float, __builtin_amdgcn_readlane(ai, 0));
            float a32 = __builtin_bit_cast(float, __builtin_amdgcn_readlane(ai, 32));
            if (tl == 0) hpool[(size_t)i * EMB + e0 + eb + r] = (a0 - a32) / 15.0f;
        }
    }
}

// ---- topk body: radix select, wave-level scans (shared layout in smem) ----
__device__ __forceinline__ void topk_body(char* smem, int c,
                                          const float* __restrict__ caps,
                                          int* __restrict__ idxs,
                                          float* __restrict__ vals) {
    float* rowf = (float*)smem;                                // 9600 B
    unsigned(*hist)[256] = (unsigned(*)[256])(smem + 9600);    // 4096 B
    unsigned* scanbuf = (unsigned*)(smem + 13696);             // 1024 B
    unsigned* wtot = (unsigned*)(smem + 14720);                // 16 B
    ull* sprefix = (ull*)(smem + 14744);                       // 8 B
    int* srank = (int*)(smem + 14752);                         // 4 B
    int tid = threadIdx.x;
    int w = tid >> 6, lane = tid & 63;
    const float4* src = (const float4*)(caps + (size_t)c * EMB);
    for (int j = tid; j < EMB / 4; j += 256) {
        float4 v = src[j];
        *(float4*)&rowf[j * 4] = v;
    }
    if (tid == 0) { *sprefix = 0ull; *srank = ATTK; }
#pragma unroll 1
    for (int pass = 0; pass < 6; ++pass) {
        __syncthreads();
        ull pref = *sprefix;
        int rk = *srank;
        int shift = 40 - pass * 8;
        ull pmaskhi = (pass == 0) ? 0ull : ~((1ull << (shift + 8)) - 1ull);
        hist[0][tid] = 0; hist[1][tid] = 0; hist[2][tid] = 0; hist[3][tid] = 0;
        __syncthreads();
        unsigned* myhist = hist[w];
#pragma unroll 1
        for (int s = 0; s < 10; s++) {
            int e = tid + s * 256;
            if (e < EMB) {
                ull key = ((ull)f2sort(rowf[e]) << 16) | ((unsigned)(2399 - e) << 4);
                if ((key & pmaskhi) == pref)
                    atomicAdd(&myhist[(unsigned)(key >> shift) & 255u], 1u);
            }
        }
        __syncthreads();
        unsigned h = hist[0][tid] + hist[1][tid] + hist[2][tid] + hist[3][tid];
        scanbuf[255 - tid] = h;
        __syncthreads();
        unsigned x = scanbuf[tid];
#pragma unroll
        for (int d = 1; d < 64; d <<= 1) {
            unsigned u = __shfl_up(x, d, 64);
            if (lane >= d) x += u;
        }
        if (lane == 63) wtot[w] = x;
        __syncthreads();
        unsigned off = 0;
        for (int ww = 0; ww < w; ww++) off += wtot[ww];
        scanbuf[tid] = x + off;
        __syncthreads();
        unsigned incl = scanbuf[255 - tid];
        unsigned excl = incl - h;
        if (h > 0u && excl < (unsigned)rk && incl >= (unsigned)rk) {
            *srank = rk - (int)excl;
            *sprefix = pref | ((ull)tid << shift);
        }
    }
    __syncthreads();
    ull T = *sprefix;
    unsigned selmask = 0, cnt = 0;
#pragma unroll 1
    for (int s = 0; s < 10; s++) {
        int e = tid + s * 256;
        if (e < EMB) {
            ull key = ((ull)f2sort(rowf[e]) << 16) | ((unsigned)(2399 - e) << 4);
            if (key >= T) { selmask |= 1u << s; cnt++; }
        }
    }
    unsigned x = cnt;
#pragma unroll
    for (int d = 1; d < 64; d <<= 1) {
        unsigned u = __shfl_up(x, d, 64);
        if (lane >= d) x += u;
    }
    if (lane == 63) wtot[w] = x;
    __syncthreads();
    unsigned off = 0;
    for (int ww = 0; ww < w; ww++) off += wtot[ww];
    unsigned slot = x + off - cnt;
#pragma unroll 1
    for (int s = 0; s < 10; s++) {
        if (selmask & (1u << s)) {
            int e = tid + s * 256;
            idxs[c * ATTK + slot] = e;
            vals[c * ATTK + slot] = fabsf(rowf[e]);
            slot++;
        }
    }
}

// ---- convw body: wbf = bf16(fc_w), 4 rows/block (wave per row) ----
__device__ __forceinline__ void convw_body(int b, const float* __restrict__ fc_w,
                                           unsigned short* __restrict__ wbf) {
    int o = b * 4 + (threadIdx.x >> 6);
    int lane = threadIdx.x & 63;
    const float* wrow = fc_w + (size_t)o * EMB;
    unsigned short* wdst = wbf + (size_t)o * EMB;
    for (int e = lane * 4; e < EMB; e += 256) {
        float4 wv = *(const float4*)&wrow[e];
        ushort4 r;
        r.x = f2bf(wv.x); r.y = f2bf(wv.y); r.z = f2bf(wv.z); r.w = f2bf(wv.w);
        *(ushort4*)&wdst[e] = r;
    }
}

// ---- combo dispatcher: [transpool 1200][convw 600][topk 64] ----
__global__ __launch_bounds__(256) void combo_kernel(const float* __restrict__ g,
                                                    float* __restrict__ hpool,
                                                    unsigned short* __restrict__ gT,
                                                    float* __restrict__ gout,
                                                    const float* __restrict__ caps,
                                                    int* __restrict__ idxs,
                                                    float* __restrict__ vals,
                                                    const float* __restrict__ fc_w,
                                                    unsigned short* __restrict__ wbf,
                                                    int nconv) {
    __shared__ __align__(16) char smem[25664];
    int b = blockIdx.x;
    constexpr int NTP = (EMB / 32) * IMGS;  // 1200
    if (b < NTP) {
        transpool_body(smem, b % (EMB / 32), b / (EMB / 32), g, hpool, gT, gout);
    } else if (b < NTP + nconv) {
        convw_body(b - NTP, fc_w, wbf);
    } else {
        topk_body(smem, b - NTP - nconv, caps, idxs, vals);
    }
}

// ---------------- x (fallback, fp32 weights) ----------------
__global__ void x_kernel(const float* __restrict__ hpool, const float* __restrict__ fc_w,
                         const float* __restrict__ fc_b, float* __restrict__ x_out) {
    int o = blockIdx.x;
    int lane = threadIdx.x;
    float acc[IMGS];
#pragma unroll
    for (int i = 0; i < IMGS; i++) acc[i] = 0.f;
    const float* wrow = fc_w + (size_t)o * EMB;
    for (int e = lane; e < EMB; e += 64) {
        float wv = wrow[e];
#pragma unroll
        for (int i = 0; i < IMGS; i++) acc[i] += hpool[i * EMB + e] * wv;
    }
#pragma unroll
    for (int i = 0; i < IMGS; i++) {
#pragma unroll
        for (int sdx = 32; sdx > 0; sdx >>= 1) acc[i] += __shfl_xor(acc[i], sdx, 64);
    }
    if (lane == 0) {
        float bo = fc_b[o];
#pragma unroll
        for (int i = 0; i < IMGS; i++) x_out[i * EMB + o] = acc[i] + bo;
    }
}

// ======== NT bf16 MFMA GEMM, gll staging, 3-buffer counted-vmcnt pipeline ========
// T1 bijective XCD swizzle + y-major; T2 source/read swizzle; T4 counted vmcnt;
// T5 setprio. OUT_MODE 6: signed bf16. OUT_MODE 4: f32 v*invS[z*64+row]+bias[col].
template <int MF, int NF, int OUT_MODE>
__global__ __launch_bounds__(256) void gemm_gll(const unsigned short* __restrict__ A,
                                                const unsigned short* __restrict__ B,
                                                void* __restrict__ outp,
                                                const float* __restrict__ bias,
                                                const float* __restrict__ invS,
                                                int M, int N, int K, int ldb, int kper,
                                                long az, long bz) {
    constexpr int BM = MF * 32, BN = NF * 32;
    constexpr int ROWS = BM + BN;
    constexpr int RPAD = (ROWS + 63) & ~63;
    constexpr int NCALL = RPAD / 16;
    constexpr int LPW = NCALL / 4;
    __shared__ unsigned short lds[3][RPAD][32];
    int gx = gridDim.x, gy = gridDim.y;
    int nwg = gx * gy;
    int flat = blockIdx.y * gx + blockIdx.x;
    int qq = nwg >> 3, rr8 = nwg & 7;
    int xcd = flat & 7, idx = flat >> 3;
    int base = (xcd < rr8) ? xcd * (qq + 1) : rr8 * (qq + 1) + (xcd - rr8) * qq;
    int nf = base + idx;
    int m0 = (nf % gy) * BM;
    int n0 = (nf / gy) * BN;
    int z = blockIdx.z;
    const unsigned short* Ab = A + (size_t)z * az;
    const unsigned short* Bb = B + (size_t)z * bz;
    int kb = (az == 0 && bz == 0) ? z * kper : 0;
    int nt = kper / 32;
    int tid = threadIdx.x, w = tid >> 6, lane = tid & 63;
    int wm = (w >> 1) * (MF * 16), wn = (w & 1) * (NF * 16);
    int ln = lane & 15;
    int ks = (((lane >> 4) ^ ((lane >> 1) & 3))) * 8;
    int srow = lane >> 2;
    int skc = (((lane & 3) ^ ((lane >> 3) & 3))) * 8;

    auto STAGE = [&](int buf, int t) {
        int k0 = kb + t * 32;
#pragma unroll
        for (int j = 0; j < LPW; j++) {
            int jj = w + j * 4;
            int r = jj * 16 + srow;
            const unsigned short* src;
            if (r < BM) src = Ab + (size_t)(m0 + r) * K + k0 + skc;
            else if (r < ROWS) src = Bb + (size_t)(n0 + r - BM) * ldb + k0 + skc;
            else src = Ab + (size_t)m0 * K + k0 + skc;  // dummy (uniform vmcnt)
            __builtin_amdgcn_global_load_lds((gas1_t)(const void*)src,
                                             (las3_t)(void*)&lds[buf][jj * 16][0], 16, 0, 0);
        }
    };

    STAGE(0, 0);
    if (nt > 1) STAGE(1, 1);
    f32x4 acc[MF][NF] = {};
    for (int t = 0; t < nt; ++t) {
        if (t + 1 < nt) {
            if constexpr (LPW == 4) asm volatile("s_waitcnt vmcnt(4) lgkmcnt(0)" ::: "memory");
            else if constexpr (LPW == 5) asm volatile("s_waitcnt vmcnt(5) lgkmcnt(0)" ::: "memory");
            else if constexpr (LPW == 6) asm volatile("s_waitcnt vmcnt(6) lgkmcnt(0)" ::: "memory");
            else asm volatile("s_waitcnt vmcnt(0) lgkmcnt(0)" ::: "memory");
        } else {
            asm volatile("s_waitcnt vmcnt(0) lgkmcnt(0)" ::: "memory");
        }
        __builtin_amdgcn_s_barrier();
        __builtin_amdgcn_sched_barrier(0);  // rule #18
        if (t + 2 < nt) STAGE((t + 2) % 3, t + 2);
        const unsigned short(*buf)[32] = lds[t % 3];
        short8 af[MF], bfv[NF];
#pragma unroll
        for (int mf = 0; mf < MF; mf++)
            af[mf] = *(const short8*)&buf[wm + mf * 16 + ln][ks];
#pragma unroll
        for (int nfi = 0; nfi < NF; nfi++)
            bfv[nfi] = *(const short8*)&buf[BM + wn + nfi * 16 + ln][ks];
        __builtin_amdgcn_s_setprio(1);  // T5
#pragma unroll
        for (int mf = 0; mf < MF; mf++)
#pragma unroll
            for (int nfi = 0; nfi < NF; nfi++)
                acc[mf][nfi] = __builtin_amdgcn_mfma_f32_16x16x32_bf16(af[mf], bfv[nfi],
                                                                       acc[mf][nfi], 0, 0, 0);
        __builtin_amdgcn_s_setprio(0);
    }
#pragma unroll
    for (int mf = 0; mf < MF; mf++) {
#pragma unroll
        for (int nfi = 0; nfi < NF; nfi++) {
#pragma unroll
            for (int rr = 0; rr < 4; rr++) {
                int row = m0 + wm + mf * 16 + (lane >> 4) * 4 + rr;
                int col = n0 + wn + nfi * 16 + ln;
                float v = acc[mf][nfi][rr];
                if (OUT_MODE == 6) {
                    ((unsigned short*)outp)[(size_t)row * N + col] = f2bf(v);
                } else if (OUT_MODE == 4) {
                    ((float*)outp)[((size_t)z * CAPS + row) * N + col] =
                        v * invS[z * CAPS + row] + bias[col];
                }
            }
        }
    }
}

// ======== fallback reg-staged NT GEMM (gemm1 only; used if ws too small for wbf) ========
__device__ inline uint4 load8(const unsigned short* p) { return *(const uint4*)p; }
__device__ inline uint4 load8(const float* p) {
    float4 a = *(const float4*)p;
    float4 b = *(const float4*)(p + 4);
    uint4 r;
    r.x = (unsigned)f2bf(a.x) | ((unsigned)f2bf(a.y) << 16);
    r.y = (unsigned)f2bf(a.z) | ((unsigned)f2bf(a.w) << 16);
    r.z = (unsigned)f2bf(b.x) | ((unsigned)f2bf(b.y) << 16);
    r.w = (unsigned)f2bf(b.z) | ((unsigned)f2bf(b.w) << 16);
    return r;
}

template <int MF, int NF, typename TA, typename TB>
__global__ __launch_bounds__(256) void mfma_gemm_nt(const TA* __restrict__ A,
                                                    const TB* __restrict__ B,
                                                    void* __restrict__ outp,
                                                    int M, int N, int K) {
    constexpr int BM = MF * 32, BN = NF * 32;
    constexpr int nA = BM * 4, nTot = (BM + BN) * 4;
    constexpr int NCH = (nTot + 255) / 256;
    __shared__ unsigned short As[BM][40];
    __shared__ unsigned short Bs[BN][40];
    int m0 = blockIdx.y * BM, n0 = blockIdx.x * BN;
    int tid = threadIdx.x;
    int w = tid >> 6, lane = tid & 63;
    int wm = (w >> 1) * (MF * 16), wn = (w & 1) * (NF * 16);
    int ln = lane & 15, ks = (lane >> 4) * 8;
    uint4 r[NCH];
#pragma unroll
    for (int j = 0; j < NCH; j++) {
        int c = tid + 256 * j;
        if (c < nTot) {
            if (c < nA) {
                int row = c >> 2, kc = c & 3;
                r[j] = load8(A + (size_t)(m0 + row) * K + kc * 8);
            } else {
                int cc = c - nA, row = cc >> 2, kc = cc & 3;
                r[j] = load8(B + (size_t)(n0 + row) * K + kc * 8);
            }
        }
    }
    f32x4 acc[MF][NF] = {};
    for (int k0 = 0; k0 < K; k0 += 32) {
#pragma unroll
        for (int j = 0; j < NCH; j++) {
            int c = tid + 256 * j;
            if (c < nTot) {
                if (c < nA) {
                    int row = c >> 2, kc = c & 3;
                    *(uint4*)&As[row][kc * 8] = r[j];
                } else {
                    int cc = c - nA, row = cc >> 2, kc = cc & 3;
                    *(uint4*)&Bs[row][kc * 8] = r[j];
                }
            }
        }
        __syncthreads();
        if (k0 + 32 < K) {
#pragma unroll
            for (int j = 0; j < NCH; j++) {
                int c = tid + 256 * j;
                if (c < nTot) {
                    if (c < nA) {
                        int row = c >> 2, kc = c & 3;
                        r[j] = load8(A + (size_t)(m0 + row) * K + (k0 + 32) + kc * 8);
                    } else {
                        int cc = c - nA, row = cc >> 2, kc = cc & 3;
                        r[j] = load8(B + (size_t)(n0 + row) * K + (k0 + 32) + kc * 8);
                    }
                }
            }
        }
        short8 af[MF], bfv[NF];
#pragma unroll
        for (int mf = 0; mf < MF; mf++)
            af[mf] = *(const short8*)&As[wm + mf * 16 + ln][ks];
#pragma unroll
        for (int nfi = 0; nfi < NF; nfi++)
            bfv[nfi] = *(const short8*)&Bs[wn + nfi * 16 + ln][ks];
#pragma unroll
        for (int mf = 0; mf < MF; mf++)
#pragma unroll
            for (int nfi = 0; nfi < NF; nfi++)
                acc[mf][nfi] = __builtin_amdgcn_mfma_f32_16x16x32_bf16(af[mf], bfv[nfi],
                                                                       acc[mf][nfi], 0, 0, 0);
        __syncthreads();
    }
#pragma unroll
    for (int mf = 0; mf < MF; mf++) {
#pragma unroll
        for (int nfi = 0; nfi < NF; nfi++) {
#pragma unroll
            for (int rr = 0; rr < 4; rr++) {
                int row = m0 + wm + mf * 16 + (lane >> 4) * 4 + rr;
                int col = n0 + wn + nfi * 16 + ln;
                ((unsigned short*)outp)[(size_t)row * N + col] = f2bf(acc[mf][nfi][rr]);
            }
        }
    }
}

// ======== heatx: heat (i,c)-blocks + x_bf blocks in one dispatch ========
// b < nheat: heat body (fused pad-zero + invS). b >= nheat: x = hpool@wbf^T + b.
__global__ __launch_bounds__(256) void heatx_kernel(const int* __restrict__ idxs,
                                                    const float* __restrict__ vals,
                                                    const unsigned short* __restrict__ A,
                                                    unsigned short* __restrict__ Hnbf,
                                                    float* __restrict__ invS,
                                                    const float* __restrict__ hpool,
                                                    const unsigned short* __restrict__ wbf,
                                                    const float* __restrict__ fc_b,
                                                    float* __restrict__ x_out,
                                                    int nheat) {
    __shared__ int sidx[ATTK];
    __shared__ float sval[ATTK];
    __shared__ float wsum[4];
    int b = blockIdx.x;
    int tid = threadIdx.x;
    int w = tid >> 6, lane = tid & 63;
    if (b < nheat) {
        int i = b % IMGS, c = b / IMGS;
        if (tid < ATTK) {
            sidx[tid] = idxs[c * ATTK + tid];
            sval[tid] = vals[c * ATTK + tid];
        }
        __syncthreads();
        int hw = tid;
        float v = 0.f;
        if (hw < HW) {
            int n = i * HW + hw;
            float a0 = 0.f, a1 = 0.f, a2 = 0.f, a3 = 0.f;
#pragma unroll 1
            for (int j = 0; j < ATTK; j += 4) {
                a0 += sval[j + 0] * bf2f(A[(size_t)sidx[j + 0] * NCOLS + n] & 0x7FFFu);
                a1 += sval[j + 1] * bf2f(A[(size_t)sidx[j + 1] * NCOLS + n] & 0x7FFFu);
                a2 += sval[j + 2] * bf2f(A[(size_t)sidx[j + 2] * NCOLS + n] & 0x7FFFu);
                a3 += sval[j + 3] * bf2f(A[(size_t)sidx[j + 3] * NCOLS + n] & 0x7FFFu);
            }
            v = (a0 + a1) + (a2 + a3);
        }
        if (hw < KPAD)
            Hnbf[((size_t)i * CAPS + c) * KPAD + hw] =
                (hw < HW) ? f2bf(v) : (unsigned short)0;
        float s = v;
#pragma unroll
        for (int d = 32; d > 0; d >>= 1) s += __shfl_xor(s, d, 64);
        if (lane == 0) wsum[w] = s;
        __syncthreads();
        if (tid == 0)
            invS[i * CAPS + c] = 1.0f / (wsum[0] + wsum[1] + wsum[2] + wsum[3]);
    } else {
        int o = (b - nheat) * 4 + w;
        float acc[IMGS];
#pragma unroll
        for (int i = 0; i < IMGS; i++) acc[i] = 0.f;
        const unsigned short* wrow = wbf + (size_t)o * EMB;
        for (int e = lane * 4; e < EMB; e += 256) {
            ushort4 wq = *(const ushort4*)&wrow[e];
            float w0 = bf2f(wq.x), w1 = bf2f(wq.y), w2 = bf2f(wq.z), w3 = bf2f(wq.w);
#pragma unroll
            for (int i = 0; i < IMGS; i++) {
                const float* hp = hpool + i * EMB + e;
                acc[i] += hp[0] * w0 + hp[1] * w1 + hp[2] * w2 + hp[3] * w3;
            }
        }
#pragma unroll
        for (int i = 0; i < IMGS; i++) {
#pragma unroll
            for (int sdx = 32; sdx > 0; sdx >>= 1) acc[i] += __shfl_xor(acc[i], sdx, 64);
        }
        if (lane == 0) {
            float bo = fc_b[o];
#pragma unroll
            for (int i = 0; i < IMGS; i++) x_out[i * EMB + o] = acc[i] + bo;
        }
    }
}

extern "C" void kernel_launch(void* const* d_in, const int* in_sizes, int n_in,
                              void* d_out, int out_size, void* d_ws, size_t ws_size,
                              hipStream_t stream) {
    const float* g = (const float*)d_in[0];
    const float* caps = (const float*)d_in[1];
    const float* fc_w = (const float*)d_in[2];
    const float* fc_b = (const float*)d_in[3];

    float* out = (float*)d_out;
    float* x_out = out;                    // 38400
    float* xa_out = out + 38400;           // 2457600
    float* g_out = out + 38400 + 2457600;  // 7526400 floats = 30.1 MB

    float* ws = (float*)d_ws;
    float* hpool = ws;                                       // 38400 f
    int* idxs = (int*)(ws + 38400);                          // 11520
    float* vals = ws + 49920;                                // 11520
    float* invS = ws + 61440;                                // 1024 f
    unsigned short* Hnbf = (unsigned short*)(ws + 62464);    // 16*64*224 us
    unsigned short* wbf = (unsigned short*)(ws + 1490944);   // ends byte 17483776
    bool use_wbf = ws_size >= (size_t)17483776;
    bool ws_big = use_wbf && ws_size >= (size_t)(17483776 + 2 * 15052800);
    unsigned short* gT_big = (unsigned short*)((char*)d_ws + 17483776);
    unsigned short* Asig_big = (unsigned short*)((char*)d_ws + 17483776 + 15052800);

    // fallback tier: scratch in g_out ([Asig][gT] exact fit), memcpy at end.
    // xa-gemm K-tail (k=196..223) reads <=27 elems past an image slice into
    // initialized finite data x Hn-pad=0 -> exact 0 (both tiers).
    unsigned short* Asig = ws_big ? Asig_big : (unsigned short*)g_out;
    unsigned short* gT = ws_big ? gT_big : ((unsigned short*)g_out + (size_t)EMB * NCOLS);

    if (use_wbf) {
        // combo: [transpool 1200][convw 600][topk 64] -- VALU-heavy first
        combo_kernel<<<(EMB / 32) * IMGS + EMB / 4 + CAPS, 256, 0, stream>>>(
            g, hpool, gT, ws_big ? g_out : nullptr, caps, idxs, vals, fc_w, wbf, EMB / 4);
        // gemm1 (5,7): signed Asig; BM=160 (15), BN=224 (14) -> 210 blocks
        gemm_gll<5, 7, 6><<<dim3(NCOLS / 224, EMB / 160, 1), 256, 0, stream>>>(
            wbf, gT, Asig, nullptr, nullptr, EMB, NCOLS, EMB, EMB, EMB, 0, 0);
        // heat (1024 blocks) + x_bf (600 blocks) co-dispatched
        heatx_kernel<<<IMGS * CAPS + EMB / 4, 256, 0, stream>>>(
            idxs, vals, Asig, Hnbf, invS, hpool, wbf, fc_b, x_out, IMGS * CAPS);
    } else {
        combo_kernel<<<(EMB / 32) * IMGS + CAPS, 256, 0, stream>>>(
            g, hpool, gT, nullptr, caps, idxs, vals, fc_w, nullptr, 0);
        x_kernel<<<EMB, 64, 0, stream>>>(hpool, fc_w, fc_b, x_out);
        mfma_gemm_nt<5, 2, float, unsigned short>
            <<<dim3(NCOLS / 64, EMB / 160), 256, 0, stream>>>(fc_w, gT, Asig,
                                                              EMB, NCOLS, EMB);
        heatx_kernel<<<IMGS * CAPS, 256, 0, stream>>>(
            idxs, vals, Asig, Hnbf, invS, hpool, nullptr, fc_b, x_out, IMGS * CAPS);
    }
    // xa = (Hraw_i @ Asig_i^T) * invS + bias : per-image batched GEMM
    gemm_gll<2, 5, 4><<<dim3(EMB / 160, 1, IMGS), 256, 0, stream>>>(
        Hnbf, Asig, xa_out, fc_b, invS, CAPS, EMB, KPAD, NCOLS, KPAD,
        (long)CAPS * KPAD, HW);
    if (!ws_big) {
        hipMemcpyAsync(g_out, g, sizeof(float) * (size_t)IMGS * EMB * HW,
                       hipMemcpyDeviceToDevice, stream);
    }
}